// Round 12
// baseline (76.684 us; speedup 1.0000x reference)
//
#include <hip/hip_runtime.h>
#include <hip/hip_cooperative_groups.h>
#include <math.h>

namespace cg = cooperative_groups;

#define NB 64
#define NT 4096
#define NU 512
#define NL 128
#define HALF 64

typedef __bf16 bf16x8 __attribute__((ext_vector_type(8)));
typedef float f32x4 __attribute__((ext_vector_type(4)));

__device__ inline unsigned short f2bf(float f) {
    unsigned u = __float_as_uint(f);
    u += 0x7fff + ((u >> 16) & 1);   // RNE
    return (unsigned short)(u >> 16);
}

__device__ inline float tanh_fast(float x) {
    float xc = fminf(15.f, fmaxf(-15.f, x));
    float t = __expf(2.f * xc);
    return (t - 1.f) * __builtin_amdgcn_rcpf(t + 1.f);
}

// =====================================================================
// Prep (1024 blocks) — identical to round 6:
//   [0,256)    q2: block (b, cq) -> 128 cols of q2[b] = query[b]@W2 + b1 + b2
//   [256,512)  W1 -> W1T bf16 (32x32 tiled transpose)
//   [512,1024) gather windows -> bf16 Gb[b][l][u], zero-filled
// =====================================================================
__global__ __launch_bounds__(256) void k_prepA(const float* __restrict__ query,
                                               const float* __restrict__ values,
                                               const int* __restrict__ pos,
                                               const float* __restrict__ W1,
                                               const float* __restrict__ b1,
                                               const float* __restrict__ W2,
                                               const float* __restrict__ b2,
                                               float* __restrict__ q2,
                                               unsigned short* __restrict__ W1T,
                                               unsigned short* __restrict__ Gb) {
    __shared__ float sh[1056];
    const int blk = blockIdx.x, tid = threadIdx.x;

    if (blk < 256) {
        // ---- q2, col-split ----
        const int b = blk >> 2, cq = blk & 3;
        sh[tid]       = query[b * NU + tid];
        sh[tid + 256] = query[b * NU + tid + 256];
        __syncthreads();
        const int col  = cq * 128 + (tid & 127);
        const int half = tid >> 7;
        const float* wp = W2 + (size_t)(half * 256) * NU + col;
        float a = 0.f;
        #pragma unroll 8
        for (int uu = 0; uu < 256; ++uu)
            a = fmaf(sh[half * 256 + uu], wp[(size_t)uu * NU], a);
        if (half == 0) sh[512 + (tid & 127)] = a;
        __syncthreads();
        if (half == 1)
            q2[(size_t)b * NU + col] = a + sh[512 + (tid & 127)] + b1[col] + b2[col];
    } else if (blk < 512) {
        // ---- W1 transpose -> bf16 ----
        const int t  = blk - 256;            // 16x16 grid of 32x32 tiles
        const int tr = t >> 4, tc = t & 15;
        const int cc = tid & 31, r0 = tid >> 5;
        #pragma unroll
        for (int i = 0; i < 4; ++i) {
            const int r = r0 + i * 8;
            sh[r * 33 + cc] = W1[(size_t)(tr * 32 + r) * NU + tc * 32 + cc];
        }
        __syncthreads();
        #pragma unroll
        for (int i = 0; i < 4; ++i) {
            const int r = r0 + i * 8;
            W1T[(size_t)(tc * 32 + r) * NU + tr * 32 + cc] = f2bf(sh[cc * 33 + r]);
        }
    } else {
        // ---- gather + bf16 convert, zero-fill ----
        const int g = blk - 512;             // 0..511, 16 window-rows each
        #pragma unroll
        for (int i = 0; i < 8; ++i) {
            const int c   = tid + i * 256;   // 0..2047 float4 chunks
            const int rl  = c >> 7;          // 0..15
            const int off = (c & 127) * 4;
            const int rg  = g * 16 + rl;     // global row in [0, 8192)
            const int b   = rg >> 7, l = rg & 127;
            const int p     = pos[b];
            const int start = max(p - HALF, 0);
            const int xlen  = min(p + HALF, NT) - start;
            float4 v = make_float4(0.f, 0.f, 0.f, 0.f);
            if (l < xlen)
                v = *(const float4*)&values[((size_t)(b * NT + start + l)) * NU + off];
            uint2 pk;
            pk.x = f2bf(v.x) | ((unsigned)f2bf(v.y) << 16);
            pk.y = f2bf(v.z) | ((unsigned)f2bf(v.w) << 16);
            *(uint2*)&Gb[(size_t)rg * NU + off] = pk;
        }
    }
}

// =====================================================================
// Cooperative score + ctx. Grid 512 x 256 (2 blocks/CU, co-resident).
// Phase 1: exact round-6 score body -> part.  grid.sync().
// Phase 2: per block (b = rb>>1): softmax recompute (R7-proven agent-
// scope part loads), then context for 64 u's (u0 = nb*128 + (rb&1)*64).
// =====================================================================
__global__ __launch_bounds__(256, 2) void k_scctx(const unsigned short* __restrict__ Gb,
                                                  const unsigned short* __restrict__ W1T,
                                                  const float* __restrict__ q2,
                                                  const float* __restrict__ V,
                                                  const float* __restrict__ values,
                                                  const int* __restrict__ pos,
                                                  const float* __restrict__ bV,
                                                  float* __restrict__ part,
                                                  float* __restrict__ out) {
    __shared__ unsigned short As[64 * 64];    // 8 KB,  row stride 128 B, XOR-swizzled
    __shared__ unsigned short Bs[128 * 64];   // 16 KB, row stride 128 B, XOR-swizzled
    __shared__ float pl[64][2];
    __shared__ float wsm[NL];
    __shared__ float red[4];
    __shared__ float cp[4][64];

    const int id = blockIdx.x;
    const int nb = id >> 7, rb = id & 127;
    const int b  = rb >> 1, l0 = (rb & 1) * 64, n0 = nb * 128;
    const int tid = threadIdx.x, lane = tid & 63, w = tid >> 6;
    const int wr = w >> 1, wc = w & 1;        // wave = 32 rows x 64 cols

    const unsigned short* Asrc = Gb + ((size_t)(b * NL + l0)) * NU;
    const unsigned short* Bsrc = W1T + (size_t)n0 * NU;

    f32x4 acc[2][4];
    #pragma unroll
    for (int m = 0; m < 2; ++m)
        #pragma unroll
        for (int n = 0; n < 4; ++n) acc[m][n] = (f32x4){0.f, 0.f, 0.f, 0.f};

    for (int k0 = 0; k0 < NU; k0 += 64) {
        // stage A: 64 rows x 64 k bf16 = 512 uint4 chunks, 2/thread
        #pragma unroll
        for (int i = 0; i < 2; ++i) {
            const int c   = tid + i * 256;
            const int row = c >> 3, ch = c & 7;
            uint4 v = *(const uint4*)&Asrc[(size_t)row * NU + k0 + ch * 8];
            *(uint4*)((char*)As + row * 128 + ((ch * 16) ^ ((row & 7) << 4))) = v;
        }
        // stage B: 128 cols x 64 k bf16 = 1024 uint4 chunks, 4/thread
        #pragma unroll
        for (int i = 0; i < 4; ++i) {
            const int c   = tid + i * 256;
            const int col = c >> 3, ch = c & 7;
            uint4 v = *(const uint4*)&Bsrc[(size_t)col * NU + k0 + ch * 8];
            *(uint4*)((char*)Bs + col * 128 + ((ch * 16) ^ ((col & 7) << 4))) = v;
        }
        __syncthreads();

        #pragma unroll
        for (int kh = 0; kh < 2; ++kh) {
            const int koff = kh * 64 + (lane >> 4) * 16;   // byte offset in 128B row
            bf16x8 af[2];
            #pragma unroll
            for (int m = 0; m < 2; ++m) {
                const int rowA = wr * 32 + m * 16 + (lane & 15);
                af[m] = *(const bf16x8*)((const char*)As + rowA * 128 + (koff ^ ((rowA & 7) << 4)));
            }
            #pragma unroll
            for (int n = 0; n < 4; ++n) {
                const int colB = wc * 64 + n * 16 + (lane & 15);
                const bf16x8 bf = *(const bf16x8*)((const char*)Bs + colB * 128 + (koff ^ ((colB & 7) << 4)));
                #pragma unroll
                for (int m = 0; m < 2; ++m)
                    acc[m][n] = __builtin_amdgcn_mfma_f32_16x16x32_bf16(af[m], bf, acc[m][n], 0, 0, 0);
            }
        }
        __syncthreads();
    }

    // epilogue: row partials over this wave's 64 cols
    float partial[2][4];
    #pragma unroll
    for (int m = 0; m < 2; ++m)
        #pragma unroll
        for (int r = 0; r < 4; ++r) partial[m][r] = 0.f;

    #pragma unroll
    for (int n = 0; n < 4; ++n) {
        const int col = n0 + wc * 64 + n * 16 + (lane & 15);
        const float qq = q2[(size_t)b * NU + col];
        const float vv = V[col];
        #pragma unroll
        for (int m = 0; m < 2; ++m)
            #pragma unroll
            for (int r = 0; r < 4; ++r)
                partial[m][r] += tanh_fast(acc[m][n][r] + qq) * vv;
    }
    #pragma unroll
    for (int off = 1; off < 16; off <<= 1)
        #pragma unroll
        for (int m = 0; m < 2; ++m)
            #pragma unroll
            for (int r = 0; r < 4; ++r)
                partial[m][r] += __shfl_xor(partial[m][r], off, 16);

    if ((lane & 15) == 0) {
        #pragma unroll
        for (int m = 0; m < 2; ++m)
            #pragma unroll
            for (int r = 0; r < 4; ++r)
                pl[wr * 32 + m * 16 + ((lane >> 4) << 2) + r][wc] = partial[m][r];
    }
    __syncthreads();

    if (tid < 64) {
        part[((size_t)nb * NB + b) * NL + l0 + tid] = pl[tid][0] + pl[tid][1];
        __threadfence();
    }

    // ---------------- grid-wide barrier ----------------
    cg::this_grid().sync();

    // ---------------- phase 2: softmax + context ----------------
    float s = -1e30f;
    if (tid < NL) {
        s = bV[0];
        #pragma unroll
        for (int q = 0; q < 4; ++q)
            s += __hip_atomic_load(&part[((size_t)q * NB + b) * NL + tid],
                                   __ATOMIC_RELAXED, __HIP_MEMORY_SCOPE_AGENT);
    }
    float m = s;
    #pragma unroll
    for (int off = 32; off >= 1; off >>= 1) m = fmaxf(m, __shfl_xor(m, off, 64));
    if (tid < NL && (tid & 63) == 0) red[tid >> 6] = m;
    __syncthreads();
    const float M = fmaxf(red[0], red[1]);
    const float e = (tid < NL) ? __expf(s - M) : 0.f;
    float t = e;
    #pragma unroll
    for (int off = 32; off >= 1; off >>= 1) t += __shfl_xor(t, off, 64);
    if (tid < NL && (tid & 63) == 0) red[2 + (tid >> 6)] = t;
    __syncthreads();
    const float S = red[2] + red[3];
    if (tid < NL) {
        const float wv = e / S;
        wsm[tid] = wv;
        if (id < NB * 2 && (rb & 1) == 0 && nb == 0) { /* unreachable combo guard */ }
        if (nb == 0 && (rb & 1) == 0) out[NB * NU + b * NL + tid] = wv;
    }
    __syncthreads();

    const int p     = pos[b];
    const int start = max(p - HALF, 0);
    const int xlen  = min(p + HALF, NT) - start;
    const float* vbase = values + ((size_t)b * NT + start) * NU;

    const int u    = n0 + l0 /*(rb&1)*64*/ + (lane & 63) - l0 + l0; // u0 + lane
    const int uu   = n0 + (rb & 1) * 64 + lane;
    const int lbeg = w * 32;
    const int lend = min(xlen, lbeg + 32);
    float a = 0.f;
    #pragma unroll 4
    for (int l = lbeg; l < lend; ++l)
        a = fmaf(wsm[l], vbase[(size_t)l * NU + uu], a);
    cp[w][lane] = a;
    __syncthreads();
    if (tid < 64)
        out[b * NU + (n0 + (rb & 1) * 64 + tid)] =
            cp[0][tid] + cp[1][tid] + cp[2][tid] + cp[3][tid];
    (void)u;
}

// =====================================================================
// FALLBACK PATH (proven fp32) — used only if ws too small
// =====================================================================
#define BM 64
#define BN 128
#define BK 64
#define ASTRIDE 68

__global__ __launch_bounds__(256) void k_q2(const float* __restrict__ query,
                                            const float* __restrict__ W2,
                                            const float* __restrict__ b2,
                                            const float* __restrict__ b1,
                                            float* __restrict__ q2) {
    const int b = blockIdx.x, tid = threadIdx.x;
    __shared__ float qs[NU];
    qs[tid]       = query[b * NU + tid];
    qs[tid + 256] = query[b * NU + tid + 256];
    __syncthreads();
    float a0 = 0.f, a1 = 0.f;
    const float* w = W2 + tid;
    #pragma unroll 8
    for (int u = 0; u < NU; ++u) {
        const float q = qs[u];
        a0 = fmaf(q, w[(size_t)u * NU], a0);
        a1 = fmaf(q, w[(size_t)u * NU + 256], a1);
    }
    q2[b * NU + tid]       = a0 + b2[tid] + b1[tid];
    q2[b * NU + tid + 256] = a1 + b2[tid + 256] + b1[tid + 256];
}

__global__ __launch_bounds__(256) void k_score(const float* __restrict__ values,
                                               const int* __restrict__ pos,
                                               const float* __restrict__ W1,
                                               const float* __restrict__ V,
                                               const float* __restrict__ q2,
                                               float* __restrict__ part) {
    __shared__ float As2[BK][ASTRIDE];
    __shared__ float Bs2[BK][BN];
    const int rb = blockIdx.x, nb = blockIdx.y;
    const int b  = rb >> 1;
    const int l0 = (rb & 1) * BM;
    const int n0 = nb * BN;
    const int tid = threadIdx.x;
    const int tx = tid & 15, ty = tid >> 4;
    const int p     = pos[b];
    const int start = max(p - HALF, 0);
    const int xlen  = min(p + HALF, NT) - start;
    const float* vbase = values + ((size_t)b * NT + start) * NU;

    float acc[4][8];
    #pragma unroll
    for (int r = 0; r < 4; ++r)
        #pragma unroll
        for (int c = 0; c < 8; ++c) acc[r][c] = 0.f;

    for (int k0 = 0; k0 < NU; k0 += BK) {
        #pragma unroll
        for (int i = 0; i < 4; ++i) {
            const int f = tid + i * 256;
            const int row = f >> 4, kq = f & 15;
            const int l = l0 + row;
            float4 v4 = make_float4(0.f, 0.f, 0.f, 0.f);
            if (l < xlen)
                v4 = *(const float4*)&vbase[(size_t)l * NU + k0 + kq * 4];
            As2[kq * 4 + 0][row] = v4.x;
            As2[kq * 4 + 1][row] = v4.y;
            As2[kq * 4 + 2][row] = v4.z;
            As2[kq * 4 + 3][row] = v4.w;
        }
        #pragma unroll
        for (int i = 0; i < 8; ++i) {
            const int f = tid + i * 256;
            const int kk = f >> 5, nq = f & 31;
            *(float4*)&Bs2[kk][nq * 4] =
                *(const float4*)&W1[(size_t)(k0 + kk) * NU + n0 + nq * 4];
        }
        __syncthreads();
        #pragma unroll 16
        for (int kk = 0; kk < BK; ++kk) {
            const float4 a  = *(const float4*)&As2[kk][ty * 4];
            const float4 b0 = *(const float4*)&Bs2[kk][tx * 8];
            const float4 b1v = *(const float4*)&Bs2[kk][tx * 8 + 4];
            const float av[4] = {a.x, a.y, a.z, a.w};
            const float bv[8] = {b0.x, b0.y, b0.z, b0.w, b1v.x, b1v.y, b1v.z, b1v.w};
            #pragma unroll
            for (int r = 0; r < 4; ++r)
                #pragma unroll
                for (int c = 0; c < 8; ++c)
                    acc[r][c] = fmaf(av[r], bv[c], acc[r][c]);
        }
        __syncthreads();
    }
    float partial[4] = {0.f, 0.f, 0.f, 0.f};
    #pragma unroll
    for (int c = 0; c < 8; ++c) {
        const int v = n0 + tx * 8 + c;
        const float vv = V[v];
        const float qq = q2[b * NU + v];
        #pragma unroll
        for (int r = 0; r < 4; ++r)
            partial[r] += tanhf(acc[r][c] + qq) * vv;
    }
    #pragma unroll
    for (int off = 1; off < 16; off <<= 1)
        #pragma unroll
        for (int r = 0; r < 4; ++r)
            partial[r] += __shfl_xor(partial[r], off, 16);
    if (tx == 0) {
        #pragma unroll
        for (int r = 0; r < 4; ++r) {
            const int l = l0 + ty * 4 + r;
            part[((size_t)nb * NB + b) * NL + l] = partial[r];
        }
    }
}

__global__ __launch_bounds__(256) void k_ctx(const float* __restrict__ values,
                                             const int* __restrict__ pos,
                                             const float* __restrict__ part,
                                             const float* __restrict__ bV,
                                             float* __restrict__ out) {
    const int b = blockIdx.x, tid = threadIdx.x;
    __shared__ float wsh[NL];
    __shared__ float red2[4];

    float s = -1e30f;
    if (tid < NL) {
        s = bV[0];
        #pragma unroll
        for (int nb = 0; nb < 4; ++nb) s += part[((size_t)nb * NB + b) * NL + tid];
    }
    float m = s;
    #pragma unroll
    for (int off = 32; off >= 1; off >>= 1) m = fmaxf(m, __shfl_xor(m, off, 64));
    if (tid < NL && (tid & 63) == 0) red2[tid >> 6] = m;
    __syncthreads();
    const float M = fmaxf(red2[0], red2[1]);
    const float e = (tid < NL) ? expf(s - M) : 0.f;
    float t = e;
    #pragma unroll
    for (int off = 32; off >= 1; off >>= 1) t += __shfl_xor(t, off, 64);
    if (tid < NL && (tid & 63) == 0) red2[2 + (tid >> 6)] = t;
    __syncthreads();
    const float S = red2[2] + red2[3];
    if (tid < NL) wsh[tid] = e / S;
    __syncthreads();

    if (tid < NL) out[NB * NU + b * NL + tid] = wsh[tid];

    const int p     = pos[b];
    const int start = max(p - HALF, 0);
    const int xlen  = min(p + HALF, NT) - start;
    const float* vb = values + ((size_t)b * NT + start) * NU;

    float a0 = 0.f, a1 = 0.f;
    for (int l = 0; l < xlen; ++l) {
        const float wl = wsh[l];
        a0 = fmaf(wl, vb[(size_t)l * NU + tid], a0);
        a1 = fmaf(wl, vb[(size_t)l * NU + tid + 256], a1);
    }
    out[b * NU + tid]       = a0;
    out[b * NU + tid + 256] = a1;
}

// =====================================================================
extern "C" void kernel_launch(void* const* d_in, const int* in_sizes, int n_in,
                              void* d_out, int out_size, void* d_ws, size_t ws_size,
                              hipStream_t stream) {
    const float* query  = (const float*)d_in[0];
    const float* values = (const float*)d_in[1];
    const int*   pos    = (const int*)d_in[2];
    const float* W1     = (const float*)d_in[3];
    const float* b1     = (const float*)d_in[4];
    const float* W2     = (const float*)d_in[5];
    const float* b2     = (const float*)d_in[6];
    const float* V      = (const float*)d_in[7];
    const float* bV     = (const float*)d_in[8];
    float* out = (float*)d_out;

    const size_t need = 131072u + 131072u + 524288u + 8388608u;   // 9.2 MB
    if (ws_size >= need) {
        float* q2            = (float*)d_ws;                              // 128 KB
        float* part          = (float*)((char*)d_ws + 131072);            // 128 KB
        unsigned short* W1T  = (unsigned short*)((char*)d_ws + 262144);   // 512 KB
        unsigned short* Gb   = (unsigned short*)((char*)d_ws + 786432);   // 8 MB
        k_prepA<<<1024, 256, 0, stream>>>(query, values, pos, W1, b1, W2, b2, q2, W1T, Gb);

        void* args[] = { (void*)&Gb, (void*)&W1T, (void*)&q2, (void*)&V,
                         (void*)&values, (void*)&pos, (void*)&bV,
                         (void*)&part, (void*)&out };
        hipLaunchCooperativeKernel((void*)k_scctx, dim3(512), dim3(256),
                                   args, 0, stream);
    } else {
        float* q2   = (float*)d_ws;
        float* part = (float*)((char*)d_ws + 131072);
        k_q2<<<NB, 256, 0, stream>>>(query, W2, b2, b1, q2);
        k_score<<<dim3(NB * NL / BM, NU / BN), 256, 0, stream>>>(values, pos, W1, V, q2, part);
        k_ctx<<<NB, 256, 0, stream>>>(values, pos, part, bV, out);
    }
}

// Round 14
// 35.755 us; speedup vs baseline: 2.1447x; 2.1447x over previous
//
#include <hip/hip_runtime.h>
#include <math.h>

#define NB 64
#define NT 4096
#define NU 512
#define NL 128
#define HALF 64

typedef __bf16 bf16x8 __attribute__((ext_vector_type(8)));
typedef float f32x4 __attribute__((ext_vector_type(4)));

__device__ inline unsigned short f2bf(float f) {
    unsigned u = __float_as_uint(f);
    u += 0x7fff + ((u >> 16) & 1);   // RNE
    return (unsigned short)(u >> 16);
}

__device__ inline float tanh_fast(float x) {
    float xc = fminf(15.f, fmaxf(-15.f, x));
    float t = __expf(2.f * xc);
    return (t - 1.f) * __builtin_amdgcn_rcpf(t + 1.f);
}

// =====================================================================
// Prep (1024 blocks) — identical to round 6:
//   [0,256)    q2: block (b, cq) -> 128 cols of q2[b] = query[b]@W2 + b1 + b2
//   [256,512)  W1 -> W1T bf16 (32x32 tiled transpose)
//   [512,1024) gather windows -> bf16 Gb[b][l][u], zero-filled
// =====================================================================
__global__ __launch_bounds__(256) void k_prepA(const float* __restrict__ query,
                                               const float* __restrict__ values,
                                               const int* __restrict__ pos,
                                               const float* __restrict__ W1,
                                               const float* __restrict__ b1,
                                               const float* __restrict__ W2,
                                               const float* __restrict__ b2,
                                               float* __restrict__ q2,
                                               unsigned short* __restrict__ W1T,
                                               unsigned short* __restrict__ Gb) {
    __shared__ float sh[1056];
    const int blk = blockIdx.x, tid = threadIdx.x;

    if (blk < 256) {
        // ---- q2, col-split ----
        const int b = blk >> 2, cq = blk & 3;
        sh[tid]       = query[b * NU + tid];
        sh[tid + 256] = query[b * NU + tid + 256];
        __syncthreads();
        const int col  = cq * 128 + (tid & 127);
        const int half = tid >> 7;
        const float* wp = W2 + (size_t)(half * 256) * NU + col;
        float a = 0.f;
        #pragma unroll 8
        for (int uu = 0; uu < 256; ++uu)
            a = fmaf(sh[half * 256 + uu], wp[(size_t)uu * NU], a);
        if (half == 0) sh[512 + (tid & 127)] = a;
        __syncthreads();
        if (half == 1)
            q2[(size_t)b * NU + col] = a + sh[512 + (tid & 127)] + b1[col] + b2[col];
    } else if (blk < 512) {
        // ---- W1 transpose -> bf16 ----
        const int t  = blk - 256;            // 16x16 grid of 32x32 tiles
        const int tr = t >> 4, tc = t & 15;
        const int cc = tid & 31, r0 = tid >> 5;
        #pragma unroll
        for (int i = 0; i < 4; ++i) {
            const int r = r0 + i * 8;
            sh[r * 33 + cc] = W1[(size_t)(tr * 32 + r) * NU + tc * 32 + cc];
        }
        __syncthreads();
        #pragma unroll
        for (int i = 0; i < 4; ++i) {
            const int r = r0 + i * 8;
            W1T[(size_t)(tc * 32 + r) * NU + tr * 32 + cc] = f2bf(sh[cc * 33 + r]);
        }
    } else {
        // ---- gather + bf16 convert, zero-fill ----
        const int g = blk - 512;             // 0..511, 16 window-rows each
        #pragma unroll
        for (int i = 0; i < 8; ++i) {
            const int c   = tid + i * 256;   // 0..2047 float4 chunks
            const int rl  = c >> 7;          // 0..15
            const int off = (c & 127) * 4;
            const int rg  = g * 16 + rl;     // global row in [0, 8192)
            const int b   = rg >> 7, l = rg & 127;
            const int p     = pos[b];
            const int start = max(p - HALF, 0);
            const int xlen  = min(p + HALF, NT) - start;
            float4 v = make_float4(0.f, 0.f, 0.f, 0.f);
            if (l < xlen)
                v = *(const float4*)&values[((size_t)(b * NT + start + l)) * NU + off];
            uint2 pk;
            pk.x = f2bf(v.x) | ((unsigned)f2bf(v.y) << 16);
            pk.y = f2bf(v.z) | ((unsigned)f2bf(v.w) << 16);
            *(uint2*)&Gb[(size_t)rg * NU + off] = pk;
        }
    }
}

// =====================================================================
// Score (round-6 proven body, byte-identical): 512 blocks, id = nb*128+rb
// (nb-major -> same-b blocks share an XCD L2). Block: 64 rows x 128 cols,
// K=512, BK=64. 256 thr = 4 waves (2x2), wave = 32 rows x 64 cols.
// part[nb][b][l] = sum over block's 128 cols of tanh(gemm + q2)*V
// =====================================================================
__global__ __launch_bounds__(256, 2) void k_score6(const unsigned short* __restrict__ Gb,
                                                   const unsigned short* __restrict__ W1T,
                                                   const float* __restrict__ q2,
                                                   const float* __restrict__ V,
                                                   float* __restrict__ part) {
    __shared__ unsigned short As[64 * 64];    // 8 KB,  row stride 128 B, XOR-swizzled
    __shared__ unsigned short Bs[128 * 64];   // 16 KB, row stride 128 B, XOR-swizzled
    __shared__ float pl[64][2];

    const int id = blockIdx.x;
    const int nb = id >> 7, rb = id & 127;
    const int b  = rb >> 1, l0 = (rb & 1) * 64, n0 = nb * 128;
    const int tid = threadIdx.x, lane = tid & 63, w = tid >> 6;
    const int wr = w >> 1, wc = w & 1;        // wave = 32 rows x 64 cols

    const unsigned short* Asrc = Gb + ((size_t)(b * NL + l0)) * NU;
    const unsigned short* Bsrc = W1T + (size_t)n0 * NU;

    f32x4 acc[2][4];
    #pragma unroll
    for (int m = 0; m < 2; ++m)
        #pragma unroll
        for (int n = 0; n < 4; ++n) acc[m][n] = (f32x4){0.f, 0.f, 0.f, 0.f};

    for (int k0 = 0; k0 < NU; k0 += 64) {
        // stage A: 64 rows x 64 k bf16 = 512 uint4 chunks, 2/thread
        #pragma unroll
        for (int i = 0; i < 2; ++i) {
            const int c   = tid + i * 256;
            const int row = c >> 3, ch = c & 7;
            uint4 v = *(const uint4*)&Asrc[(size_t)row * NU + k0 + ch * 8];
            *(uint4*)((char*)As + row * 128 + ((ch * 16) ^ ((row & 7) << 4))) = v;
        }
        // stage B: 128 cols x 64 k bf16 = 1024 uint4 chunks, 4/thread
        #pragma unroll
        for (int i = 0; i < 4; ++i) {
            const int c   = tid + i * 256;
            const int col = c >> 3, ch = c & 7;
            uint4 v = *(const uint4*)&Bsrc[(size_t)col * NU + k0 + ch * 8];
            *(uint4*)((char*)Bs + col * 128 + ((ch * 16) ^ ((col & 7) << 4))) = v;
        }
        __syncthreads();

        #pragma unroll
        for (int kh = 0; kh < 2; ++kh) {
            const int koff = kh * 64 + (lane >> 4) * 16;   // byte offset in 128B row
            bf16x8 af[2];
            #pragma unroll
            for (int m = 0; m < 2; ++m) {
                const int rowA = wr * 32 + m * 16 + (lane & 15);
                af[m] = *(const bf16x8*)((const char*)As + rowA * 128 + (koff ^ ((rowA & 7) << 4)));
            }
            #pragma unroll
            for (int n = 0; n < 4; ++n) {
                const int colB = wc * 64 + n * 16 + (lane & 15);
                const bf16x8 bf = *(const bf16x8*)((const char*)Bs + colB * 128 + (koff ^ ((colB & 7) << 4)));
                #pragma unroll
                for (int m = 0; m < 2; ++m)
                    acc[m][n] = __builtin_amdgcn_mfma_f32_16x16x32_bf16(af[m], bf, acc[m][n], 0, 0, 0);
            }
        }
        __syncthreads();
    }

    // epilogue: row partials over this wave's 64 cols
    float partial[2][4];
    #pragma unroll
    for (int m = 0; m < 2; ++m)
        #pragma unroll
        for (int r = 0; r < 4; ++r) partial[m][r] = 0.f;

    #pragma unroll
    for (int n = 0; n < 4; ++n) {
        const int col = n0 + wc * 64 + n * 16 + (lane & 15);
        const float qq = q2[(size_t)b * NU + col];
        const float vv = V[col];
        #pragma unroll
        for (int m = 0; m < 2; ++m)
            #pragma unroll
            for (int r = 0; r < 4; ++r)
                partial[m][r] += tanh_fast(acc[m][n][r] + qq) * vv;
    }
    #pragma unroll
    for (int off = 1; off < 16; off <<= 1)
        #pragma unroll
        for (int m = 0; m < 2; ++m)
            #pragma unroll
            for (int r = 0; r < 4; ++r)
                partial[m][r] += __shfl_xor(partial[m][r], off, 16);

    if ((lane & 15) == 0) {
        #pragma unroll
        for (int m = 0; m < 2; ++m)
            #pragma unroll
            for (int r = 0; r < 4; ++r)
                pl[wr * 32 + m * 16 + ((lane >> 4) << 2) + r][wc] = partial[m][r];
    }
    __syncthreads();

    if (tid < 64)
        part[((size_t)nb * NB + b) * NL + l0 + tid] = pl[tid][0] + pl[tid][1];
}

// =====================================================================
// Ctx: grid (64, 8) = 512 blocks. Softmax recomputed per block (cheap),
// context for a 64-u slice; l-range split across the 4 waves.
// =====================================================================
__global__ __launch_bounds__(256) void k_ctx8(const float* __restrict__ values,
                                              const int* __restrict__ pos,
                                              const float* __restrict__ part,
                                              const float* __restrict__ bV,
                                              float* __restrict__ out) {
    const int b = blockIdx.x, ue = blockIdx.y, tid = threadIdx.x;
    __shared__ float wsm[NL];
    __shared__ float red[4];
    __shared__ float cp[4][64];

    float s = -1e30f;
    if (tid < NL) {
        s = bV[0];
        #pragma unroll
        for (int nb = 0; nb < 4; ++nb) s += part[((size_t)nb * NB + b) * NL + tid];
    }
    float m = s;
    #pragma unroll
    for (int off = 32; off >= 1; off >>= 1) m = fmaxf(m, __shfl_xor(m, off, 64));
    if (tid < NL && (tid & 63) == 0) red[tid >> 6] = m;
    __syncthreads();
    const float M = fmaxf(red[0], red[1]);
    const float e = (tid < NL) ? __expf(s - M) : 0.f;
    float t = e;
    #pragma unroll
    for (int off = 32; off >= 1; off >>= 1) t += __shfl_xor(t, off, 64);
    if (tid < NL && (tid & 63) == 0) red[2 + (tid >> 6)] = t;
    __syncthreads();
    const float S = red[2] + red[3];
    if (tid < NL) {
        const float wv = e / S;
        wsm[tid] = wv;
        if (ue == 0) out[NB * NU + b * NL + tid] = wv;
    }
    __syncthreads();

    const int p     = pos[b];
    const int start = max(p - HALF, 0);
    const int xlen  = min(p + HALF, NT) - start;
    const float* vbase = values + ((size_t)b * NT + start) * NU;

    const int u    = ue * 64 + (tid & 63);
    const int lseg = tid >> 6;
    const int lbeg = lseg * 32;
    const int lend = min(xlen, lbeg + 32);
    float a = 0.f;
    #pragma unroll 4
    for (int l = lbeg; l < lend; ++l)
        a = fmaf(wsm[l], vbase[(size_t)l * NU + u], a);

    cp[lseg][tid & 63] = a;
    __syncthreads();
    if (tid < 64)
        out[b * NU + ue * 64 + tid] = cp[0][tid] + cp[1][tid] + cp[2][tid] + cp[3][tid];
}

// =====================================================================
// FALLBACK PATH (proven fp32) — used only if ws too small
// =====================================================================
#define BM 64
#define BN 128
#define BK 64
#define ASTRIDE 68

__global__ __launch_bounds__(256) void k_q2(const float* __restrict__ query,
                                            const float* __restrict__ W2,
                                            const float* __restrict__ b2,
                                            const float* __restrict__ b1,
                                            float* __restrict__ q2) {
    const int b = blockIdx.x, tid = threadIdx.x;
    __shared__ float qs[NU];
    qs[tid]       = query[b * NU + tid];
    qs[tid + 256] = query[b * NU + tid + 256];
    __syncthreads();
    float a0 = 0.f, a1 = 0.f;
    const float* w = W2 + tid;
    #pragma unroll 8
    for (int u = 0; u < NU; ++u) {
        const float q = qs[u];
        a0 = fmaf(q, w[(size_t)u * NU], a0);
        a1 = fmaf(q, w[(size_t)u * NU + 256], a1);
    }
    q2[b * NU + tid]       = a0 + b2[tid] + b1[tid];
    q2[b * NU + tid + 256] = a1 + b2[tid + 256] + b1[tid + 256];
}

__global__ __launch_bounds__(256) void k_score(const float* __restrict__ values,
                                               const int* __restrict__ pos,
                                               const float* __restrict__ W1,
                                               const float* __restrict__ V,
                                               const float* __restrict__ q2,
                                               float* __restrict__ part) {
    __shared__ float As2[BK][ASTRIDE];
    __shared__ float Bs2[BK][BN];
    const int rb = blockIdx.x, nb = blockIdx.y;
    const int b  = rb >> 1;
    const int l0 = (rb & 1) * BM;
    const int n0 = nb * BN;
    const int tid = threadIdx.x;
    const int tx = tid & 15, ty = tid >> 4;
    const int p     = pos[b];
    const int start = max(p - HALF, 0);
    const int xlen  = min(p + HALF, NT) - start;
    const float* vbase = values + ((size_t)b * NT + start) * NU;

    float acc[4][8];
    #pragma unroll
    for (int r = 0; r < 4; ++r)
        #pragma unroll
        for (int c = 0; c < 8; ++c) acc[r][c] = 0.f;

    for (int k0 = 0; k0 < NU; k0 += BK) {
        #pragma unroll
        for (int i = 0; i < 4; ++i) {
            const int f = tid + i * 256;
            const int row = f >> 4, kq = f & 15;
            const int l = l0 + row;
            float4 v4 = make_float4(0.f, 0.f, 0.f, 0.f);
            if (l < xlen)
                v4 = *(const float4*)&vbase[(size_t)l * NU + k0 + kq * 4];
            As2[kq * 4 + 0][row] = v4.x;
            As2[kq * 4 + 1][row] = v4.y;
            As2[kq * 4 + 2][row] = v4.z;
            As2[kq * 4 + 3][row] = v4.w;
        }
        #pragma unroll
        for (int i = 0; i < 8; ++i) {
            const int f = tid + i * 256;
            const int kk = f >> 5, nq = f & 31;
            *(float4*)&Bs2[kk][nq * 4] =
                *(const float4*)&W1[(size_t)(k0 + kk) * NU + n0 + nq * 4];
        }
        __syncthreads();
        #pragma unroll 16
        for (int kk = 0; kk < BK; ++kk) {
            const float4 a  = *(const float4*)&As2[kk][ty * 4];
            const float4 b0 = *(const float4*)&Bs2[kk][tx * 8];
            const float4 b1v = *(const float4*)&Bs2[kk][tx * 8 + 4];
            const float av[4] = {a.x, a.y, a.z, a.w};
            const float bv[8] = {b0.x, b0.y, b0.z, b0.w, b1v.x, b1v.y, b1v.z, b1v.w};
            #pragma unroll
            for (int r = 0; r < 4; ++r)
                #pragma unroll
                for (int c = 0; c < 8; ++c)
                    acc[r][c] = fmaf(av[r], bv[c], acc[r][c]);
        }
        __syncthreads();
    }
    float partial[4] = {0.f, 0.f, 0.f, 0.f};
    #pragma unroll
    for (int c = 0; c < 8; ++c) {
        const int v = n0 + tx * 8 + c;
        const float vv = V[v];
        const float qq = q2[b * NU + v];
        #pragma unroll
        for (int r = 0; r < 4; ++r)
            partial[r] += tanhf(acc[r][c] + qq) * vv;
    }
    #pragma unroll
    for (int off = 1; off < 16; off <<= 1)
        #pragma unroll
        for (int r = 0; r < 4; ++r)
            partial[r] += __shfl_xor(partial[r], off, 16);
    if (tx == 0) {
        #pragma unroll
        for (int r = 0; r < 4; ++r) {
            const int l = l0 + ty * 4 + r;
            part[((size_t)nb * NB + b) * NL + l] = partial[r];
        }
    }
}

__global__ __launch_bounds__(256) void k_ctx(const float* __restrict__ values,
                                             const int* __restrict__ pos,
                                             const float* __restrict__ part,
                                             const float* __restrict__ bV,
                                             float* __restrict__ out) {
    const int b = blockIdx.x, tid = threadIdx.x;
    __shared__ float wsh[NL];
    __shared__ float red2[4];

    float s = -1e30f;
    if (tid < NL) {
        s = bV[0];
        #pragma unroll
        for (int nb = 0; nb < 4; ++nb) s += part[((size_t)nb * NB + b) * NL + tid];
    }
    float m = s;
    #pragma unroll
    for (int off = 32; off >= 1; off >>= 1) m = fmaxf(m, __shfl_xor(m, off, 64));
    if (tid < NL && (tid & 63) == 0) red2[tid >> 6] = m;
    __syncthreads();
    const float M = fmaxf(red2[0], red2[1]);
    const float e = (tid < NL) ? expf(s - M) : 0.f;
    float t = e;
    #pragma unroll
    for (int off = 32; off >= 1; off >>= 1) t += __shfl_xor(t, off, 64);
    if (tid < NL && (tid & 63) == 0) red2[2 + (tid >> 6)] = t;
    __syncthreads();
    const float S = red2[2] + red2[3];
    if (tid < NL) wsh[tid] = e / S;
    __syncthreads();

    if (tid < NL) out[NB * NU + b * NL + tid] = wsh[tid];

    const int p     = pos[b];
    const int start = max(p - HALF, 0);
    const int xlen  = min(p + HALF, NT) - start;
    const float* vb = values + ((size_t)b * NT + start) * NU;

    float a0 = 0.f, a1 = 0.f;
    for (int l = 0; l < xlen; ++l) {
        const float wl = wsh[l];
        a0 = fmaf(wl, vb[(size_t)l * NU + tid], a0);
        a1 = fmaf(wl, vb[(size_t)l * NU + tid + 256], a1);
    }
    out[b * NU + tid]       = a0;
    out[b * NU + tid + 256] = a1;
}

// =====================================================================
extern "C" void kernel_launch(void* const* d_in, const int* in_sizes, int n_in,
                              void* d_out, int out_size, void* d_ws, size_t ws_size,
                              hipStream_t stream) {
    const float* query  = (const float*)d_in[0];
    const float* values = (const float*)d_in[1];
    const int*   pos    = (const int*)d_in[2];
    const float* W1     = (const float*)d_in[3];
    const float* b1     = (const float*)d_in[4];
    const float* W2     = (const float*)d_in[5];
    const float* b2     = (const float*)d_in[6];
    const float* V      = (const float*)d_in[7];
    const float* bV     = (const float*)d_in[8];
    float* out = (float*)d_out;

    const size_t need = 131072u + 131072u + 524288u + 8388608u;   // 9.2 MB
    if (ws_size >= need) {
        float* q2            = (float*)d_ws;                              // 128 KB
        float* part          = (float*)((char*)d_ws + 131072);            // 128 KB
        unsigned short* W1T  = (unsigned short*)((char*)d_ws + 262144);   // 512 KB
        unsigned short* Gb   = (unsigned short*)((char*)d_ws + 786432);   // 8 MB
        k_prepA<<<1024, 256, 0, stream>>>(query, values, pos, W1, b1, W2, b2, q2, W1T, Gb);
        k_score6<<<512, 256, 0, stream>>>(Gb, W1T, q2, V, part);
        k_ctx8<<<dim3(NB, 8), 256, 0, stream>>>(values, pos, part, bV, out);
    } else {
        float* q2   = (float*)d_ws;
        float* part = (float*)((char*)d_ws + 131072);
        k_q2<<<NB, 256, 0, stream>>>(query, W2, b2, b1, q2);
        k_score<<<dim3(NB * NL / BM, NU / BN), 256, 0, stream>>>(values, pos, W1, V, q2, part);
        k_ctx<<<NB, 256, 0, stream>>>(values, pos, part, bV, out);
    }
}